// Round 4
// baseline (1491.066 us; speedup 1.0000x reference)
//
#include <hip/hip_runtime.h>
#include <stdint.h>

#define N_PTS 100000
#define M_PTS 131072

typedef unsigned short u16;
typedef __attribute__((ext_vector_type(8))) short bf16x8;
typedef __attribute__((ext_vector_type(4))) float f32x4;

__device__ __forceinline__ u16 f2bf(float x) {
    union { float f; uint32_t u; } v; v.f = x;
    uint32_t r = v.u + 0x7fffu + ((v.u >> 16) & 1u);
    return (u16)(r >> 16);
}
__device__ __forceinline__ float bf2f(u16 b) {
    union { uint32_t u; float f; } v; v.u = ((uint32_t)b) << 16;
    return v.f;
}
__device__ __forceinline__ bf16x8 cvt8(const float* __restrict__ p) {
    float4 x0 = *(const float4*)p;
    float4 x1 = *(const float4*)(p + 4);
    bf16x8 r;
    r[0]=(short)f2bf(x0.x); r[1]=(short)f2bf(x0.y);
    r[2]=(short)f2bf(x0.z); r[3]=(short)f2bf(x0.w);
    r[4]=(short)f2bf(x1.x); r[5]=(short)f2bf(x1.y);
    r[6]=(short)f2bf(x1.z); r[7]=(short)f2bf(x1.w);
    return r;
}

// ---------------- K0: preconvert weights to bf16 (L2-resident B) -----------
__global__ __launch_bounds__(256) void conv_weights(
    const float* __restrict__ Wqkv, const float* __restrict__ Wproj,
    u16* __restrict__ Wqkvb, u16* __restrict__ Wprojb)
{
    int i = blockIdx.x*256 + threadIdx.x;   // grid 768
    Wqkvb[i] = f2bf(Wqkv[i]);
    if (i < 65536) Wprojb[i] = f2bf(Wproj[i]);
}

// ---------------- K1: qkv = feat @ Wqkv^T + bqkv  -> bf16 (N x 768) --------
// 512 threads = 8 waves (2 row-groups x 4 col-groups), A-tile (128x256 bf16,
// 64KB, XOR-swizzled) staged once, 3 jt panels of 256 cols. 8 waves/CU.
__global__ __launch_bounds__(512) void qkv_gemm(
    const float* __restrict__ feat, const u16* __restrict__ Wqkvb,
    const float* __restrict__ bqkv, u16* __restrict__ qkvb)
{
    const int nt = blockIdx.x;   // 0..781
    const int tid = threadIdx.x;
    __shared__ u16 at[128][256];

    {   // stage: thread t -> row t>>2, chunk set {i*4 + (t&3)} (8-elem chunks)
        const int row = tid >> 2, q = tid & 3;
        const int grow = nt*128 + row;
        const int swb = row & 7;
        if (grow < N_PTS) {
            const float* src = feat + (size_t)grow*256;
            #pragma unroll
            for (int i=0;i<8;i++) {
                int c = i*4 + q;                 // lanes 0-3 cover 128B contiguous
                bf16x8 v = cvt8(src + c*8);
                *(bf16x8*)&at[row][(c^swb)*8] = v;
            }
        } else {
            #pragma unroll
            for (int i=0;i<8;i++) {
                int c = i*4 + q;
                *(bf16x8*)&at[row][(c^swb)*8] = (bf16x8)0;
            }
        }
    }
    __syncthreads();

    const int w = tid>>6, l = tid&63, lr = l&15, lk = l>>4;
    const int r0 = (w>>2)*64;
    const int n0 = nt*128 + r0;
    const int swr = lr & 7;

    for (int jt=0; jt<3; jt++) {
        const int j0 = jt*256 + (w&3)*64;
        f32x4 acc[4][4];
        #pragma unroll
        for (int a=0;a<4;a++)
          #pragma unroll
          for (int b=0;b<4;b++) acc[a][b] = (f32x4)0.0f;

        for (int k=0;k<256;k+=32) {
            const int cc = (k>>3) + lk;
            bf16x8 af[4], bfr[4];
            #pragma unroll
            for (int f=0;f<4;f++)
                af[f] = *(const bf16x8*)&at[r0 + f*16 + lr][(cc^swr)*8];
            #pragma unroll
            for (int f=0;f<4;f++)
                bfr[f] = *(const bf16x8*)(Wqkvb + (size_t)(j0 + f*16 + lr)*256 + k + lk*8);
            #pragma unroll
            for (int a=0;a<4;a++)
              #pragma unroll
              for (int b=0;b<4;b++)
                acc[a][b] = __builtin_amdgcn_mfma_f32_16x16x32_bf16(af[a], bfr[b], acc[a][b], 0,0,0);
        }
        #pragma unroll
        for (int a=0;a<4;a++) {
          #pragma unroll
          for (int b=0;b<4;b++) {
            int col = j0 + b*16 + lr;
            float bias = bqkv[col];
            #pragma unroll
            for (int r=0;r<4;r++) {
                int row = n0 + a*16 + lk*4 + r;
                if (row < N_PTS)
                    qkvb[(size_t)row*768 + col] = f2bf(acc[a][b][r] + bias);
            }
          }
        }
    }
}

// ---------------- K2: gather + RoPE + blocked attention --------------------
__global__ __launch_bounds__(256) void attn_kernel(
    const u16* __restrict__ qkvb, const int* __restrict__ pinv,
    const float* __restrict__ cosb, const float* __restrict__ sinb,
    u16* __restrict__ attnout)
{
    const int h = blockIdx.x;    // 0..7
    const int p = blockIdx.y;    // 0..1023
    const int tid = threadIdx.x;

    __shared__ u16 qb[128][40];
    __shared__ u16 kb[128][40];
    __shared__ u16 vT[32][136];
    __shared__ u16 Pb[128][136];

    {   // gather + RoPE: 2 threads per token (part0: Q, part1: K + V)
        const int i = tid >> 1, part = tid & 1;
        const int m = p*128 + i;
        const int r = pinv[m];
        const u16* base = qkvb + (size_t)r*768 + part*256 + h*32;
        u16 vals[32];
        *(uint4*)(vals+0)  = *(const uint4*)(base+0);
        *(uint4*)(vals+8)  = *(const uint4*)(base+8);
        *(uint4*)(vals+16) = *(const uint4*)(base+16);
        *(uint4*)(vals+24) = *(const uint4*)(base+24);
        const float* cr = cosb + (size_t)m*32;
        const float* sr = sinb + (size_t)m*32;
        u16 o[32];
        #pragma unroll
        for (int d=0; d<16; d++) {
            float x1 = bf2f(vals[d]), x2 = bf2f(vals[d+16]);
            float c = cr[d], s = sr[d];
            o[d]    = f2bf(x1*c - x2*s);
            o[d+16] = f2bf(x2*c + x1*s);
        }
        u16 (*dst)[40] = part ? kb : qb;
        *(uint4*)&dst[i][0]  = *(uint4*)(o+0);
        *(uint4*)&dst[i][8]  = *(uint4*)(o+8);
        *(uint4*)&dst[i][16] = *(uint4*)(o+16);
        *(uint4*)&dst[i][24] = *(uint4*)(o+24);
        if (part) {
            const u16* vbase = qkvb + (size_t)r*768 + 512 + h*32;
            #pragma unroll
            for (int dd=0; dd<32; dd+=8) {
                u16 tv[8];
                *(uint4*)tv = *(const uint4*)(vbase+dd);
                #pragma unroll
                for (int b=0;b<8;b++) vT[dd+b][i] = tv[b];
            }
        }
    }
    __syncthreads();

    const int w = tid>>6, l = tid&63, lr = l&15, lk = l>>4;
    const float scale = 0.17677669529663687f;   // 1/sqrt(32)

    f32x4 sf[2][8];
    #pragma unroll
    for (int mt=0; mt<2; mt++) {
        const int rb = w*32 + mt*16;
        bf16x8 a = *(const bf16x8*)&qb[rb+lr][lk*8];
        #pragma unroll
        for (int nt=0; nt<8; nt++) {
            bf16x8 b = *(const bf16x8*)&kb[nt*16+lr][lk*8];
            sf[mt][nt] = __builtin_amdgcn_mfma_f32_16x16x32_bf16(a, b, (f32x4)0.0f, 0,0,0);
        }
    }
    #pragma unroll
    for (int mt=0; mt<2; mt++) {
      #pragma unroll
      for (int r=0; r<4; r++) {
        float mx = -1e30f;
        #pragma unroll
        for (int nt=0; nt<8; nt++) {
            sf[mt][nt][r] *= scale;
            mx = fmaxf(mx, sf[mt][nt][r]);
        }
        #pragma unroll
        for (int msk=1; msk<16; msk<<=1) mx = fmaxf(mx, __shfl_xor(mx, msk));
        float sum = 0.f;
        #pragma unroll
        for (int nt=0; nt<8; nt++) {
            float e = __expf(sf[mt][nt][r] - mx);
            sf[mt][nt][r] = e;
            sum += e;
        }
        #pragma unroll
        for (int msk=1; msk<16; msk<<=1) sum += __shfl_xor(sum, msk);
        float inv = 1.f / sum;
        int row = w*32 + mt*16 + lk*4 + r;
        #pragma unroll
        for (int nt=0; nt<8; nt++)
            Pb[row][nt*16+lr] = f2bf(sf[mt][nt][r] * inv);
      }
    }
    #pragma unroll
    for (int mt=0; mt<2; mt++) {
        const int rb = w*32 + mt*16;
        #pragma unroll
        for (int nt=0; nt<2; nt++) {
            f32x4 acc = (f32x4)0.0f;
            #pragma unroll
            for (int ks=0; ks<4; ks++) {
                bf16x8 a = *(const bf16x8*)&Pb[rb+lr][ks*32 + lk*8];
                bf16x8 b = *(const bf16x8*)&vT[nt*16+lr][ks*32 + lk*8];
                acc = __builtin_amdgcn_mfma_f32_16x16x32_bf16(a, b, acc, 0,0,0);
            }
            #pragma unroll
            for (int r=0;r<4;r++) {
                int token = p*128 + rb + lk*4 + r;
                attnout[(size_t)token*256 + h*32 + nt*16 + lr] = f2bf(acc[r]);
            }
        }
    }
}

// ---------------- K3: segment-sum scatter (pure BW + atomics) --------------
__global__ __launch_bounds__(256) void segsum_kernel(
    const u16* __restrict__ attnout, const int* __restrict__ pinv,
    float* __restrict__ sums)
{
    int idx = blockIdx.x*256 + threadIdx.x;     // grid 16384 -> M*32
    int m = idx >> 5, c8 = idx & 31;
    int seg = pinv[m];
    bf16x8 v = *(const bf16x8*)(attnout + (size_t)m*256 + c8*8);
    float* dst = sums + (size_t)seg*256 + c8*8;
    #pragma unroll
    for (int j=0;j<8;j++) atomicAdd(dst+j, bf2f((u16)v[j]));
}

// ---------------- K4: segment counts ---------------------------------------
__global__ __launch_bounds__(256) void count_kernel(const int* __restrict__ pinv,
                                                    float* __restrict__ cnt)
{
    int m = blockIdx.x*256 + threadIdx.x;
    if (m < M_PTS) atomicAdd(cnt + pinv[m], 1.0f);
}

// ---------------- K5: out = (sums/cnt) @ Wproj^T + bproj (0 if cnt==0) -----
// Same 8-wave structure as qkv_gemm; single 256-col panel; writes f32 out.
__global__ __launch_bounds__(512) void mean_proj(
    const float* __restrict__ sums, const float* __restrict__ cnt,
    const u16* __restrict__ Wprojb, const float* __restrict__ bproj,
    float* __restrict__ out)
{
    const int nt = blockIdx.x;   // 0..781
    const int tid = threadIdx.x;
    __shared__ u16 at[128][256];

    {
        const int row = tid >> 2, q = tid & 3;
        const int grow = nt*128 + row;
        const int swb = row & 7;
        if (grow < N_PTS) {
            float c = cnt[grow];
            float inv = (c > 0.f) ? 1.f/c : 0.f;
            const float* src = sums + (size_t)grow*256;
            #pragma unroll
            for (int i=0;i<8;i++) {
                int cix = i*4 + q;
                float tmp[8];
                *(float4*)(tmp+0) = *(const float4*)(src + cix*8);
                *(float4*)(tmp+4) = *(const float4*)(src + cix*8 + 4);
                bf16x8 v;
                #pragma unroll
                for (int j=0;j<8;j++) v[j] = (short)f2bf(tmp[j]*inv);
                *(bf16x8*)&at[row][(cix^swb)*8] = v;
            }
        } else {
            #pragma unroll
            for (int i=0;i<8;i++) {
                int cix = i*4 + q;
                *(bf16x8*)&at[row][(cix^swb)*8] = (bf16x8)0;
            }
        }
    }
    __syncthreads();

    const int w = tid>>6, l = tid&63, lr = l&15, lk = l>>4;
    const int r0 = (w>>2)*64;
    const int n0 = nt*128 + r0;
    const int j0 = (w&3)*64;
    const int swr = lr & 7;

    f32x4 acc[4][4];
    #pragma unroll
    for (int a=0;a<4;a++)
      #pragma unroll
      for (int b=0;b<4;b++) acc[a][b] = (f32x4)0.0f;

    for (int k=0;k<256;k+=32) {
        const int cc = (k>>3) + lk;
        bf16x8 af[4], bfr[4];
        #pragma unroll
        for (int f=0;f<4;f++)
            af[f] = *(const bf16x8*)&at[r0 + f*16 + lr][(cc^swr)*8];
        #pragma unroll
        for (int f=0;f<4;f++)
            bfr[f] = *(const bf16x8*)(Wprojb + (size_t)(j0 + f*16 + lr)*256 + k + lk*8);
        #pragma unroll
        for (int a=0;a<4;a++)
          #pragma unroll
          for (int b=0;b<4;b++)
            acc[a][b] = __builtin_amdgcn_mfma_f32_16x16x32_bf16(af[a], bfr[b], acc[a][b], 0,0,0);
    }
    #pragma unroll
    for (int a=0;a<4;a++) {
      #pragma unroll
      for (int b=0;b<4;b++) {
        int col = j0 + b*16 + lr;
        float bias = bproj[col];
        #pragma unroll
        for (int r=0;r<4;r++) {
            int row = n0 + a*16 + lk*4 + r;
            if (row < N_PTS) {
                float c = cnt[row];
                out[(size_t)row*256 + col] = (c > 0.f) ? acc[a][b][r] + bias : 0.f;
            }
        }
      }
    }
}

extern "C" void kernel_launch(void* const* d_in, const int* in_sizes, int n_in,
                              void* d_out, int out_size, void* d_ws, size_t ws_size,
                              hipStream_t stream)
{
    const float* feat  = (const float*)d_in[0];
    const int*   pinv  = (const int*)d_in[2];
    const float* cosb  = (const float*)d_in[4];
    const float* sinb  = (const float*)d_in[5];
    const float* Wqkv  = (const float*)d_in[6];
    const float* bqkv  = (const float*)d_in[7];
    const float* Wproj = (const float*)d_in[8];
    const float* bproj = (const float*)d_in[9];
    float* out = (float*)d_out;

    char* ws = (char*)d_ws;
    u16* qkvb = (u16*)ws;                                  // 153.6 MB (dead after attn)
    float* sums = (float*)ws;                              // 102.4 MB, OVERLAPS qkvb
    size_t off0 = (size_t)N_PTS*768*2;
    u16* attnout = (u16*)(ws + off0);                      // 67.1 MB
    size_t off1 = off0 + (size_t)M_PTS*256*2;
    float* cnt = (float*)(ws + off1);                      // 0.4 MB
    size_t off2 = off1 + (size_t)N_PTS*4;
    u16* Wqkvb = (u16*)(ws + off2);                        // 0.39 MB
    size_t off3 = off2 + (size_t)768*256*2;
    u16* Wprojb = (u16*)(ws + off3);                       // 0.13 MB

    hipMemsetAsync(cnt, 0, (size_t)N_PTS*sizeof(float), stream);

    conv_weights <<<768, 256, 0, stream>>>(Wqkv, Wproj, Wqkvb, Wprojb);
    count_kernel <<<512, 256, 0, stream>>>(pinv, cnt);
    qkv_gemm     <<<782, 512, 0, stream>>>(feat, Wqkvb, bqkv, qkvb);
    attn_kernel  <<<dim3(8, 1024), 256, 0, stream>>>(qkvb, pinv, cosb, sinb, attnout);
    // qkvb dead from here; reuse its space for segment sums
    hipMemsetAsync(sums, 0, (size_t)N_PTS*256*sizeof(float), stream);
    segsum_kernel<<<16384, 256, 0, stream>>>(attnout, pinv, sums);
    mean_proj    <<<782, 512, 0, stream>>>(sums, cnt, Wprojb, bproj, out);
}

// Round 5
// 595.002 us; speedup vs baseline: 2.5060x; 2.5060x over previous
//
#include <hip/hip_runtime.h>
#include <stdint.h>

#define N_PTS 100000
#define M_PTS 131072

typedef unsigned short u16;
typedef __attribute__((ext_vector_type(8))) short bf16x8;
typedef __attribute__((ext_vector_type(4))) float f32x4;

__device__ __forceinline__ u16 f2bf(float x) {
    union { float f; uint32_t u; } v; v.f = x;
    uint32_t r = v.u + 0x7fffu + ((v.u >> 16) & 1u);
    return (u16)(r >> 16);
}
__device__ __forceinline__ float bf2f(u16 b) {
    union { uint32_t u; float f; } v; v.u = ((uint32_t)b) << 16;
    return v.f;
}
__device__ __forceinline__ bf16x8 cvt8(const float* __restrict__ p) {
    float4 x0 = *(const float4*)p;
    float4 x1 = *(const float4*)(p + 4);
    bf16x8 r;
    r[0]=(short)f2bf(x0.x); r[1]=(short)f2bf(x0.y);
    r[2]=(short)f2bf(x0.z); r[3]=(short)f2bf(x0.w);
    r[4]=(short)f2bf(x1.x); r[5]=(short)f2bf(x1.y);
    r[6]=(short)f2bf(x1.z); r[7]=(short)f2bf(x1.w);
    return r;
}

// ---------------- K0: preconvert weights to bf16 (L2-resident B) -----------
__global__ __launch_bounds__(256) void conv_weights(
    const float* __restrict__ Wqkv, const float* __restrict__ Wproj,
    u16* __restrict__ Wqkvb, u16* __restrict__ Wprojb)
{
    int i = blockIdx.x*256 + threadIdx.x;   // grid 768
    Wqkvb[i] = f2bf(Wqkv[i]);
    if (i < 65536) Wprojb[i] = f2bf(Wproj[i]);
}

// ---------------- K1: qkv = feat @ Wqkv^T + bqkv  -> bf16 (N x 768) --------
// 512 threads = 8 waves (2 row-groups x 4 col-groups), A-tile (128x256 bf16,
// 64KB, XOR-swizzled) staged once, 3 jt panels of 256 cols.
__global__ __launch_bounds__(512) void qkv_gemm(
    const float* __restrict__ feat, const u16* __restrict__ Wqkvb,
    const float* __restrict__ bqkv, u16* __restrict__ qkvb)
{
    const int nt = blockIdx.x;   // 0..781
    const int tid = threadIdx.x;
    __shared__ u16 at[128][256];

    {   // stage: thread t -> row t>>2, chunk set {i*4 + (t&3)} (8-elem chunks)
        const int row = tid >> 2, q = tid & 3;
        const int grow = nt*128 + row;
        const int swb = row & 7;
        if (grow < N_PTS) {
            const float* src = feat + (size_t)grow*256;
            #pragma unroll
            for (int i=0;i<8;i++) {
                int c = i*4 + q;
                bf16x8 v = cvt8(src + c*8);
                *(bf16x8*)&at[row][(c^swb)*8] = v;
            }
        } else {
            #pragma unroll
            for (int i=0;i<8;i++) {
                int c = i*4 + q;
                *(bf16x8*)&at[row][(c^swb)*8] = (bf16x8)0;
            }
        }
    }
    __syncthreads();

    const int w = tid>>6, l = tid&63, lr = l&15, lk = l>>4;
    const int r0 = (w>>2)*64;
    const int n0 = nt*128 + r0;
    const int swr = lr & 7;

    for (int jt=0; jt<3; jt++) {
        const int j0 = jt*256 + (w&3)*64;
        f32x4 acc[4][4];
        #pragma unroll
        for (int a=0;a<4;a++)
          #pragma unroll
          for (int b=0;b<4;b++) acc[a][b] = (f32x4)0.0f;

        for (int k=0;k<256;k+=32) {
            const int cc = (k>>3) + lk;
            bf16x8 af[4], bfr[4];
            #pragma unroll
            for (int f=0;f<4;f++)
                af[f] = *(const bf16x8*)&at[r0 + f*16 + lr][(cc^swr)*8];
            #pragma unroll
            for (int f=0;f<4;f++)
                bfr[f] = *(const bf16x8*)(Wqkvb + (size_t)(j0 + f*16 + lr)*256 + k + lk*8);
            #pragma unroll
            for (int a=0;a<4;a++)
              #pragma unroll
              for (int b=0;b<4;b++)
                acc[a][b] = __builtin_amdgcn_mfma_f32_16x16x32_bf16(af[a], bfr[b], acc[a][b], 0,0,0);
        }
        #pragma unroll
        for (int a=0;a<4;a++) {
          #pragma unroll
          for (int b=0;b<4;b++) {
            int col = j0 + b*16 + lr;
            float bias = bqkv[col];
            #pragma unroll
            for (int r=0;r<4;r++) {
                int row = n0 + a*16 + lk*4 + r;
                if (row < N_PTS)
                    qkvb[(size_t)row*768 + col] = f2bf(acc[a][b][r] + bias);
            }
          }
        }
    }
}

// ---------------- K2: gather + RoPE + blocked attention --------------------
__global__ __launch_bounds__(256) void attn_kernel(
    const u16* __restrict__ qkvb, const int* __restrict__ pinv,
    const float* __restrict__ cosb, const float* __restrict__ sinb,
    u16* __restrict__ attnout)
{
    const int h = blockIdx.x;    // 0..7
    const int p = blockIdx.y;    // 0..1023
    const int tid = threadIdx.x;

    __shared__ u16 qb[128][40];
    __shared__ u16 kb[128][40];
    __shared__ u16 vT[32][136];
    __shared__ u16 Pb[128][136];

    {   // gather + RoPE: 2 threads per token (part0: Q, part1: K + V)
        const int i = tid >> 1, part = tid & 1;
        const int m = p*128 + i;
        const int r = pinv[m];
        const u16* base = qkvb + (size_t)r*768 + part*256 + h*32;
        u16 vals[32];
        *(uint4*)(vals+0)  = *(const uint4*)(base+0);
        *(uint4*)(vals+8)  = *(const uint4*)(base+8);
        *(uint4*)(vals+16) = *(const uint4*)(base+16);
        *(uint4*)(vals+24) = *(const uint4*)(base+24);
        const float* cr = cosb + (size_t)m*32;
        const float* sr = sinb + (size_t)m*32;
        u16 o[32];
        #pragma unroll
        for (int d=0; d<16; d++) {
            float x1 = bf2f(vals[d]), x2 = bf2f(vals[d+16]);
            float c = cr[d], s = sr[d];
            o[d]    = f2bf(x1*c - x2*s);
            o[d+16] = f2bf(x2*c + x1*s);
        }
        u16 (*dst)[40] = part ? kb : qb;
        *(uint4*)&dst[i][0]  = *(uint4*)(o+0);
        *(uint4*)&dst[i][8]  = *(uint4*)(o+8);
        *(uint4*)&dst[i][16] = *(uint4*)(o+16);
        *(uint4*)&dst[i][24] = *(uint4*)(o+24);
        if (part) {
            const u16* vbase = qkvb + (size_t)r*768 + 512 + h*32;
            #pragma unroll
            for (int dd=0; dd<32; dd+=8) {
                u16 tv[8];
                *(uint4*)tv = *(const uint4*)(vbase+dd);
                #pragma unroll
                for (int b=0;b<8;b++) vT[dd+b][i] = tv[b];
            }
        }
    }
    __syncthreads();

    const int w = tid>>6, l = tid&63, lr = l&15, lk = l>>4;
    const float scale = 0.17677669529663687f;   // 1/sqrt(32)

    f32x4 sf[2][8];
    #pragma unroll
    for (int mt=0; mt<2; mt++) {
        const int rb = w*32 + mt*16;
        bf16x8 a = *(const bf16x8*)&qb[rb+lr][lk*8];
        #pragma unroll
        for (int nt=0; nt<8; nt++) {
            bf16x8 b = *(const bf16x8*)&kb[nt*16+lr][lk*8];
            sf[mt][nt] = __builtin_amdgcn_mfma_f32_16x16x32_bf16(a, b, (f32x4)0.0f, 0,0,0);
        }
    }
    #pragma unroll
    for (int mt=0; mt<2; mt++) {
      #pragma unroll
      for (int r=0; r<4; r++) {
        float mx = -1e30f;
        #pragma unroll
        for (int nt=0; nt<8; nt++) {
            sf[mt][nt][r] *= scale;
            mx = fmaxf(mx, sf[mt][nt][r]);
        }
        #pragma unroll
        for (int msk=1; msk<16; msk<<=1) mx = fmaxf(mx, __shfl_xor(mx, msk));
        float sum = 0.f;
        #pragma unroll
        for (int nt=0; nt<8; nt++) {
            float e = __expf(sf[mt][nt][r] - mx);
            sf[mt][nt][r] = e;
            sum += e;
        }
        #pragma unroll
        for (int msk=1; msk<16; msk<<=1) sum += __shfl_xor(sum, msk);
        float inv = 1.f / sum;
        int row = w*32 + mt*16 + lk*4 + r;
        #pragma unroll
        for (int nt=0; nt<8; nt++)
            Pb[row][nt*16+lr] = f2bf(sf[mt][nt][r] * inv);
      }
    }
    #pragma unroll
    for (int mt=0; mt<2; mt++) {
        const int rb = w*32 + mt*16;
        #pragma unroll
        for (int nt=0; nt<2; nt++) {
            f32x4 acc = (f32x4)0.0f;
            #pragma unroll
            for (int ks=0; ks<4; ks++) {
                bf16x8 a = *(const bf16x8*)&Pb[rb+lr][ks*32 + lk*8];
                bf16x8 b = *(const bf16x8*)&vT[nt*16+lr][ks*32 + lk*8];
                acc = __builtin_amdgcn_mfma_f32_16x16x32_bf16(a, b, acc, 0,0,0);
            }
            #pragma unroll
            for (int r=0;r<4;r++) {
                int token = p*128 + rb + lk*4 + r;
                attnout[(size_t)token*256 + h*32 + nt*16 + lr] = f2bf(acc[r]);
            }
        }
    }
}

// ---------------- K3: bucket fill (index atomics only) ---------------------
__global__ __launch_bounds__(256) void fill_kernel(const int* __restrict__ pinv,
                                                   int* __restrict__ cursor,
                                                   int* __restrict__ list)
{
    int m = blockIdx.x*256 + threadIdx.x;
    if (m < M_PTS) {
        int seg = pinv[m];
        int slot = atomicAdd(cursor + seg, 1);
        if (slot < 32) list[seg*32 + slot] = m;
    }
}

// ---------------- K4: per-segment mean (gather-reduce, no atomics) ---------
// thread = (seg, c8): 32 cols each. 8 threads cover a 512B token row.
__global__ __launch_bounds__(256) void seg_mean(
    const u16* __restrict__ attnout, const int* __restrict__ cursor,
    const int* __restrict__ list, u16* __restrict__ meanb)
{
    int idx = blockIdx.x*256 + threadIdx.x;   // grid 3125 -> 800000
    int seg = idx >> 3, c8 = idx & 7;
    if (seg >= N_PTS) return;
    int c = cursor[seg];
    int cc = c < 32 ? c : 32;
    float acc[32];
    #pragma unroll
    for (int j=0;j<32;j++) acc[j] = 0.f;
    const int* lp = list + seg*32;
    for (int i=0;i<cc;i++) {
        int m = lp[i];
        const u16* src = attnout + (size_t)m*256 + c8*32;
        #pragma unroll
        for (int ch=0;ch<4;ch++) {
            bf16x8 v = *(const bf16x8*)(src + ch*8);
            #pragma unroll
            for (int j=0;j<8;j++) acc[ch*8+j] += bf2f((u16)v[j]);
        }
    }
    float inv = (c > 0) ? 1.f/(float)c : 0.f;
    u16* dst = meanb + (size_t)seg*256 + c8*32;
    #pragma unroll
    for (int ch=0;ch<4;ch++) {
        bf16x8 o;
        #pragma unroll
        for (int j=0;j<8;j++) o[j] = (short)f2bf(acc[ch*8+j]*inv);
        *(bf16x8*)(dst + ch*8) = o;
    }
}

// ---------------- K5: out = meanb @ Wproj^T + bproj (0 if cnt==0) ----------
__global__ __launch_bounds__(512) void mean_proj(
    const u16* __restrict__ meanb, const int* __restrict__ cursor,
    const u16* __restrict__ Wprojb, const float* __restrict__ bproj,
    float* __restrict__ out)
{
    const int nt = blockIdx.x;   // 0..781
    const int tid = threadIdx.x;
    __shared__ u16 at[128][256];

    {
        const int row = tid >> 2, q = tid & 3;
        const int grow = nt*128 + row;
        const int swb = row & 7;
        if (grow < N_PTS) {
            const u16* src = meanb + (size_t)grow*256;
            #pragma unroll
            for (int i=0;i<8;i++) {
                int cix = i*4 + q;
                bf16x8 v = *(const bf16x8*)(src + cix*8);
                *(bf16x8*)&at[row][(cix^swb)*8] = v;
            }
        } else {
            #pragma unroll
            for (int i=0;i<8;i++) {
                int cix = i*4 + q;
                *(bf16x8*)&at[row][(cix^swb)*8] = (bf16x8)0;
            }
        }
    }
    __syncthreads();

    const int w = tid>>6, l = tid&63, lr = l&15, lk = l>>4;
    const int r0 = (w>>2)*64;
    const int n0 = nt*128 + r0;
    const int j0 = (w&3)*64;
    const int swr = lr & 7;

    f32x4 acc[4][4];
    #pragma unroll
    for (int a=0;a<4;a++)
      #pragma unroll
      for (int b=0;b<4;b++) acc[a][b] = (f32x4)0.0f;

    for (int k=0;k<256;k+=32) {
        const int cc = (k>>3) + lk;
        bf16x8 af[4], bfr[4];
        #pragma unroll
        for (int f=0;f<4;f++)
            af[f] = *(const bf16x8*)&at[r0 + f*16 + lr][(cc^swr)*8];
        #pragma unroll
        for (int f=0;f<4;f++)
            bfr[f] = *(const bf16x8*)(Wprojb + (size_t)(j0 + f*16 + lr)*256 + k + lk*8);
        #pragma unroll
        for (int a=0;a<4;a++)
          #pragma unroll
          for (int b=0;b<4;b++)
            acc[a][b] = __builtin_amdgcn_mfma_f32_16x16x32_bf16(af[a], bfr[b], acc[a][b], 0,0,0);
    }
    #pragma unroll
    for (int a=0;a<4;a++) {
      #pragma unroll
      for (int b=0;b<4;b++) {
        int col = j0 + b*16 + lr;
        float bias = bproj[col];
        #pragma unroll
        for (int r=0;r<4;r++) {
            int row = n0 + a*16 + lk*4 + r;
            if (row < N_PTS) {
                int c = cursor[row];
                out[(size_t)row*256 + col] = (c > 0) ? acc[a][b][r] + bias : 0.f;
            }
        }
      }
    }
}

extern "C" void kernel_launch(void* const* d_in, const int* in_sizes, int n_in,
                              void* d_out, int out_size, void* d_ws, size_t ws_size,
                              hipStream_t stream)
{
    const float* feat  = (const float*)d_in[0];
    const int*   pinv  = (const int*)d_in[2];
    const float* cosb  = (const float*)d_in[4];
    const float* sinb  = (const float*)d_in[5];
    const float* Wqkv  = (const float*)d_in[6];
    const float* bqkv  = (const float*)d_in[7];
    const float* Wproj = (const float*)d_in[8];
    const float* bproj = (const float*)d_in[9];
    float* out = (float*)d_out;

    char* ws = (char*)d_ws;
    u16* qkvb = (u16*)ws;                                  // 153.6 MB (dead after attn)
    // overlays inside qkvb's region, used only after attn completes:
    u16* meanb = (u16*)ws;                                 // 51.2 MB  @ [0, 51.2M)
    int* list  = (int*)(ws + 70000000);                    // 12.8 MB  @ [70M, 82.8M)
    int* cursor= (int*)(ws + 90000000);                    // 0.4 MB   @ [90M, 90.4M)
    size_t off0 = (size_t)N_PTS*768*2;                     // 153.6 MB
    u16* attnout = (u16*)(ws + off0);                      // 67.1 MB
    size_t off2 = off0 + (size_t)M_PTS*256*2;
    u16* Wqkvb = (u16*)(ws + off2);                        // 0.39 MB
    size_t off3 = off2 + (size_t)768*256*2;
    u16* Wprojb = (u16*)(ws + off3);                       // 0.13 MB

    conv_weights <<<768, 256, 0, stream>>>(Wqkv, Wproj, Wqkvb, Wprojb);
    qkv_gemm     <<<782, 512, 0, stream>>>(feat, Wqkvb, bqkv, qkvb);
    attn_kernel  <<<dim3(8, 1024), 256, 0, stream>>>(qkvb, pinv, cosb, sinb, attnout);
    // qkvb dead from here; its space holds meanb/list/cursor
    hipMemsetAsync(cursor, 0, (size_t)N_PTS*sizeof(int), stream);
    fill_kernel  <<<512, 256, 0, stream>>>(pinv, cursor, list);
    seg_mean     <<<3125, 256, 0, stream>>>(attnout, cursor, list, meanb);
    mean_proj    <<<782, 512, 0, stream>>>(meanb, cursor, Wprojb, bproj, out);
}

// Round 6
// 571.201 us; speedup vs baseline: 2.6104x; 1.0417x over previous
//
#include <hip/hip_runtime.h>
#include <stdint.h>

#define N_PTS 100000
#define M_PTS 131072

typedef unsigned short u16;
typedef __attribute__((ext_vector_type(8))) short bf16x8;
typedef __attribute__((ext_vector_type(4))) float f32x4;

__device__ __forceinline__ u16 f2bf(float x) {
    union { float f; uint32_t u; } v; v.f = x;
    uint32_t r = v.u + 0x7fffu + ((v.u >> 16) & 1u);
    return (u16)(r >> 16);
}
__device__ __forceinline__ float bf2f(u16 b) {
    union { uint32_t u; float f; } v; v.u = ((uint32_t)b) << 16;
    return v.f;
}
__device__ __forceinline__ bf16x8 cvt8(const float* __restrict__ p) {
    float4 x0 = *(const float4*)p;
    float4 x1 = *(const float4*)(p + 4);
    bf16x8 r;
    r[0]=(short)f2bf(x0.x); r[1]=(short)f2bf(x0.y);
    r[2]=(short)f2bf(x0.z); r[3]=(short)f2bf(x0.w);
    r[4]=(short)f2bf(x1.x); r[5]=(short)f2bf(x1.y);
    r[6]=(short)f2bf(x1.z); r[7]=(short)f2bf(x1.w);
    return r;
}

// ---------------- K0: preconvert weights to bf16 (L2-resident B) -----------
__global__ __launch_bounds__(256) void conv_weights(
    const float* __restrict__ Wqkv, const float* __restrict__ Wproj,
    u16* __restrict__ Wqkvb, u16* __restrict__ Wprojb)
{
    int i = blockIdx.x*256 + threadIdx.x;   // grid 768
    Wqkvb[i] = f2bf(Wqkv[i]);
    if (i < 65536) Wprojb[i] = f2bf(Wproj[i]);
}

// ---------------- K1: qkv = feat @ Wqkv^T + bqkv -> bf16, layout [n][h][3][32]
// 64-row A-tile in 32KB LDS (5 blocks/CU), 8 waves x (64 rows x 32 cols),
// acc[4][2] keeps VGPR low -> 5 waves/SIMD target.
__global__ __launch_bounds__(512) void qkv_gemm(
    const float* __restrict__ feat, const u16* __restrict__ Wqkvb,
    const float* __restrict__ bqkv, u16* __restrict__ qkvb)
{
    const int nt = blockIdx.x;   // 0..1562
    const int tid = threadIdx.x;
    __shared__ u16 at[64][256];

    {   // stage: thread t -> row t>>3, chunks {q + i*8}, q=t&7 (16B chunks)
        const int row = tid >> 3, q = tid & 7;
        const int grow = nt*64 + row;
        const int swb = row & 7;
        if (grow < N_PTS) {
            const float* src = feat + (size_t)grow*256;
            #pragma unroll
            for (int i=0;i<4;i++) {
                int c = q + i*8;
                bf16x8 v = cvt8(src + c*8);
                *(bf16x8*)&at[row][(c^swb)*8] = v;
            }
        } else {
            #pragma unroll
            for (int i=0;i<4;i++) {
                int c = q + i*8;
                *(bf16x8*)&at[row][(c^swb)*8] = (bf16x8)0;
            }
        }
    }
    __syncthreads();

    const int w = tid>>6, l = tid&63, lr = l&15, lk = l>>4;
    const int n0 = nt*64;
    const int swr = lr & 7;

    for (int jt=0; jt<3; jt++) {
        const int j0 = jt*256 + w*32;
        f32x4 acc[4][2];
        #pragma unroll
        for (int a=0;a<4;a++)
          #pragma unroll
          for (int b=0;b<2;b++) acc[a][b] = (f32x4)0.0f;

        for (int k=0;k<256;k+=32) {
            const int cc = (k>>3) + lk;
            bf16x8 af[4], bfr[2];
            #pragma unroll
            for (int b=0;b<2;b++)
                bfr[b] = *(const bf16x8*)(Wqkvb + (size_t)(j0 + b*16 + lr)*256 + k + lk*8);
            #pragma unroll
            for (int f=0;f<4;f++)
                af[f] = *(const bf16x8*)&at[f*16 + lr][(cc^swr)*8];
            #pragma unroll
            for (int a=0;a<4;a++)
              #pragma unroll
              for (int b=0;b<2;b++)
                acc[a][b] = __builtin_amdgcn_mfma_f32_16x16x32_bf16(af[a], bfr[b], acc[a][b], 0,0,0);
        }
        #pragma unroll
        for (int a=0;a<4;a++) {
          #pragma unroll
          for (int b=0;b<2;b++) {
            int col = j0 + b*16 + lr;            // logical col 0..767
            float bias = bqkv[col];
            int part = col >> 8, hh = (col >> 5) & 7, d = col & 31;
            size_t cofs = (size_t)hh*96 + part*32 + d;
            #pragma unroll
            for (int r=0;r<4;r++) {
                int row = n0 + a*16 + lk*4 + r;
                if (row < N_PTS)
                    qkvb[(size_t)row*768 + cofs] = f2bf(acc[a][b][r] + bias);
            }
          }
        }
    }
}

// ---------------- K2: gather + RoPE + blocked attention --------------------
// qkvb layout: [n][h][{q,k,v}][32] -> per (token,head) 192B contiguous.
__global__ __launch_bounds__(256) void attn_kernel(
    const u16* __restrict__ qkvb, const int* __restrict__ pinv,
    const float* __restrict__ cosb, const float* __restrict__ sinb,
    u16* __restrict__ attnout)
{
    const int h = blockIdx.x;    // 0..7
    const int p = blockIdx.y;    // 0..1023
    const int tid = threadIdx.x;

    __shared__ u16 qb[128][40];
    __shared__ u16 kb[128][40];
    __shared__ u16 vT[32][136];
    __shared__ u16 Pb[128][136];

    {   // gather + RoPE: 2 threads per token (part0: Q, part1: K + V)
        const int i = tid >> 1, part = tid & 1;
        const int m = p*128 + i;
        const int r = pinv[m];
        const u16* base = qkvb + (size_t)r*768 + h*96 + part*32;
        u16 vals[32];
        *(uint4*)(vals+0)  = *(const uint4*)(base+0);
        *(uint4*)(vals+8)  = *(const uint4*)(base+8);
        *(uint4*)(vals+16) = *(const uint4*)(base+16);
        *(uint4*)(vals+24) = *(const uint4*)(base+24);
        const float* cr = cosb + (size_t)m*32;
        const float* sr = sinb + (size_t)m*32;
        u16 o[32];
        #pragma unroll
        for (int d=0; d<16; d++) {
            float x1 = bf2f(vals[d]), x2 = bf2f(vals[d+16]);
            float c = cr[d], s = sr[d];
            o[d]    = f2bf(x1*c - x2*s);
            o[d+16] = f2bf(x2*c + x1*s);
        }
        u16 (*dst)[40] = part ? kb : qb;
        *(uint4*)&dst[i][0]  = *(uint4*)(o+0);
        *(uint4*)&dst[i][8]  = *(uint4*)(o+8);
        *(uint4*)&dst[i][16] = *(uint4*)(o+16);
        *(uint4*)&dst[i][24] = *(uint4*)(o+24);
        if (part) {
            const u16* vbase = base + 32;   // V slice of this head
            #pragma unroll
            for (int dd=0; dd<32; dd+=8) {
                u16 tv[8];
                *(uint4*)tv = *(const uint4*)(vbase+dd);
                #pragma unroll
                for (int b=0;b<8;b++) vT[dd+b][i] = tv[b];
            }
        }
    }
    __syncthreads();

    const int w = tid>>6, l = tid&63, lr = l&15, lk = l>>4;
    const float scale = 0.17677669529663687f;   // 1/sqrt(32)

    f32x4 sf[2][8];
    #pragma unroll
    for (int mt=0; mt<2; mt++) {
        const int rb = w*32 + mt*16;
        bf16x8 a = *(const bf16x8*)&qb[rb+lr][lk*8];
        #pragma unroll
        for (int nt=0; nt<8; nt++) {
            bf16x8 b = *(const bf16x8*)&kb[nt*16+lr][lk*8];
            sf[mt][nt] = __builtin_amdgcn_mfma_f32_16x16x32_bf16(a, b, (f32x4)0.0f, 0,0,0);
        }
    }
    #pragma unroll
    for (int mt=0; mt<2; mt++) {
      #pragma unroll
      for (int r=0; r<4; r++) {
        float mx = -1e30f;
        #pragma unroll
        for (int nt=0; nt<8; nt++) {
            sf[mt][nt][r] *= scale;
            mx = fmaxf(mx, sf[mt][nt][r]);
        }
        #pragma unroll
        for (int msk=1; msk<16; msk<<=1) mx = fmaxf(mx, __shfl_xor(mx, msk));
        float sum = 0.f;
        #pragma unroll
        for (int nt=0; nt<8; nt++) {
            float e = __expf(sf[mt][nt][r] - mx);
            sf[mt][nt][r] = e;
            sum += e;
        }
        #pragma unroll
        for (int msk=1; msk<16; msk<<=1) sum += __shfl_xor(sum, msk);
        float inv = 1.f / sum;
        int row = w*32 + mt*16 + lk*4 + r;
        #pragma unroll
        for (int nt=0; nt<8; nt++)
            Pb[row][nt*16+lr] = f2bf(sf[mt][nt][r] * inv);
      }
    }
    #pragma unroll
    for (int mt=0; mt<2; mt++) {
        const int rb = w*32 + mt*16;
        #pragma unroll
        for (int nt=0; nt<2; nt++) {
            f32x4 acc = (f32x4)0.0f;
            #pragma unroll
            for (int ks=0; ks<4; ks++) {
                bf16x8 a = *(const bf16x8*)&Pb[rb+lr][ks*32 + lk*8];
                bf16x8 b = *(const bf16x8*)&vT[nt*16+lr][ks*32 + lk*8];
                acc = __builtin_amdgcn_mfma_f32_16x16x32_bf16(a, b, acc, 0,0,0);
            }
            #pragma unroll
            for (int r=0;r<4;r++) {
                int token = p*128 + rb + lk*4 + r;
                attnout[(size_t)token*256 + h*32 + nt*16 + lr] = f2bf(acc[r]);
            }
        }
    }
}

// ---------------- K3: bucket fill (index atomics only) ---------------------
__global__ __launch_bounds__(256) void fill_kernel(const int* __restrict__ pinv,
                                                   int* __restrict__ cursor,
                                                   int* __restrict__ list)
{
    int m = blockIdx.x*256 + threadIdx.x;
    if (m < M_PTS) {
        int seg = pinv[m];
        int slot = atomicAdd(cursor + seg, 1);
        if (slot < 32) list[seg*32 + slot] = m;
    }
}

// ---------------- K4: per-segment mean (gather-reduce, no atomics) ---------
__global__ __launch_bounds__(256) void seg_mean(
    const u16* __restrict__ attnout, const int* __restrict__ cursor,
    const int* __restrict__ list, u16* __restrict__ meanb)
{
    int idx = blockIdx.x*256 + threadIdx.x;   // grid 3125 -> 800000
    int seg = idx >> 3, c8 = idx & 7;
    if (seg >= N_PTS) return;
    int c = cursor[seg];
    int cc = c < 32 ? c : 32;
    float acc[32];
    #pragma unroll
    for (int j=0;j<32;j++) acc[j] = 0.f;
    const int* lp = list + seg*32;
    for (int i=0;i<cc;i++) {
        int m = lp[i];
        const u16* src = attnout + (size_t)m*256 + c8*32;
        #pragma unroll
        for (int ch=0;ch<4;ch++) {
            bf16x8 v = *(const bf16x8*)(src + ch*8);
            #pragma unroll
            for (int j=0;j<8;j++) acc[ch*8+j] += bf2f((u16)v[j]);
        }
    }
    float inv = (c > 0) ? 1.f/(float)c : 0.f;
    u16* dst = meanb + (size_t)seg*256 + c8*32;
    #pragma unroll
    for (int ch=0;ch<4;ch++) {
        bf16x8 o;
        #pragma unroll
        for (int j=0;j<8;j++) o[j] = (short)f2bf(acc[ch*8+j]*inv);
        *(bf16x8*)(dst + ch*8) = o;
    }
}

// ---------------- K5: out = meanb @ Wproj^T + bproj (0 if cnt==0) ----------
// Same 64-row/8-wave/acc[4][2] structure as qkv_gemm; single 256-col panel.
__global__ __launch_bounds__(512) void mean_proj(
    const u16* __restrict__ meanb, const int* __restrict__ cursor,
    const u16* __restrict__ Wprojb, const float* __restrict__ bproj,
    float* __restrict__ out)
{
    const int nt = blockIdx.x;   // 0..1562
    const int tid = threadIdx.x;
    __shared__ u16 at[64][256];

    {
        const int row = tid >> 3, q = tid & 7;
        const int grow = nt*64 + row;
        const int swb = row & 7;
        if (grow < N_PTS) {
            const u16* src = meanb + (size_t)grow*256;
            #pragma unroll
            for (int i=0;i<4;i++) {
                int c = q + i*8;
                bf16x8 v = *(const bf16x8*)(src + c*8);
                *(bf16x8*)&at[row][(c^swb)*8] = v;
            }
        } else {
            #pragma unroll
            for (int i=0;i<4;i++) {
                int c = q + i*8;
                *(bf16x8*)&at[row][(c^swb)*8] = (bf16x8)0;
            }
        }
    }
    __syncthreads();

    const int w = tid>>6, l = tid&63, lr = l&15, lk = l>>4;
    const int n0 = nt*64;
    const int j0 = w*32;
    const int swr = lr & 7;

    f32x4 acc[4][2];
    #pragma unroll
    for (int a=0;a<4;a++)
      #pragma unroll
      for (int b=0;b<2;b++) acc[a][b] = (f32x4)0.0f;

    for (int k=0;k<256;k+=32) {
        const int cc = (k>>3) + lk;
        bf16x8 af[4], bfr[2];
        #pragma unroll
        for (int b=0;b<2;b++)
            bfr[b] = *(const bf16x8*)(Wprojb + (size_t)(j0 + b*16 + lr)*256 + k + lk*8);
        #pragma unroll
        for (int f=0;f<4;f++)
            af[f] = *(const bf16x8*)&at[f*16 + lr][(cc^swr)*8];
        #pragma unroll
        for (int a=0;a<4;a++)
          #pragma unroll
          for (int b=0;b<2;b++)
            acc[a][b] = __builtin_amdgcn_mfma_f32_16x16x32_bf16(af[a], bfr[b], acc[a][b], 0,0,0);
    }
    #pragma unroll
    for (int a=0;a<4;a++) {
      #pragma unroll
      for (int b=0;b<2;b++) {
        int col = j0 + b*16 + lr;
        float bias = bproj[col];
        #pragma unroll
        for (int r=0;r<4;r++) {
            int row = n0 + a*16 + lk*4 + r;
            if (row < N_PTS) {
                int c = cursor[row];
                out[(size_t)row*256 + col] = (c > 0) ? acc[a][b][r] + bias : 0.f;
            }
        }
      }
    }
}

extern "C" void kernel_launch(void* const* d_in, const int* in_sizes, int n_in,
                              void* d_out, int out_size, void* d_ws, size_t ws_size,
                              hipStream_t stream)
{
    const float* feat  = (const float*)d_in[0];
    const int*   pinv  = (const int*)d_in[2];
    const float* cosb  = (const float*)d_in[4];
    const float* sinb  = (const float*)d_in[5];
    const float* Wqkv  = (const float*)d_in[6];
    const float* bqkv  = (const float*)d_in[7];
    const float* Wproj = (const float*)d_in[8];
    const float* bproj = (const float*)d_in[9];
    float* out = (float*)d_out;

    char* ws = (char*)d_ws;
    u16* qkvb = (u16*)ws;                                  // 153.6 MB (dead after attn)
    u16* meanb = (u16*)ws;                                 // 51.2 MB  @ [0, 51.2M)
    int* list  = (int*)(ws + 70000000);                    // 12.8 MB  @ [70M, 82.8M)
    int* cursor= (int*)(ws + 90000000);                    // 0.4 MB   @ [90M, 90.4M)
    size_t off0 = (size_t)N_PTS*768*2;                     // 153.6 MB
    u16* attnout = (u16*)(ws + off0);                      // 67.1 MB
    size_t off2 = off0 + (size_t)M_PTS*256*2;
    u16* Wqkvb = (u16*)(ws + off2);                        // 0.39 MB
    size_t off3 = off2 + (size_t)768*256*2;
    u16* Wprojb = (u16*)(ws + off3);                       // 0.13 MB

    conv_weights <<<768, 256, 0, stream>>>(Wqkv, Wproj, Wqkvb, Wprojb);
    qkv_gemm     <<<1563, 512, 0, stream>>>(feat, Wqkvb, bqkv, qkvb);
    attn_kernel  <<<dim3(8, 1024), 256, 0, stream>>>(qkvb, pinv, cosb, sinb, attnout);
    hipMemsetAsync(cursor, 0, (size_t)N_PTS*sizeof(int), stream);
    fill_kernel  <<<512, 256, 0, stream>>>(pinv, cursor, list);
    seg_mean     <<<3125, 256, 0, stream>>>(attnout, cursor, list, meanb);
    mean_proj    <<<1563, 512, 0, stream>>>(meanb, cursor, Wprojb, bproj, out);
}

// Round 7
// 517.348 us; speedup vs baseline: 2.8821x; 1.1041x over previous
//
#include <hip/hip_runtime.h>
#include <stdint.h>

#define N_PTS 100000
#define M_PTS 131072

typedef unsigned short u16;
typedef __attribute__((ext_vector_type(8))) short bf16x8;
typedef __attribute__((ext_vector_type(4))) float f32x4;

__device__ __forceinline__ u16 f2bf(float x) {
    union { float f; uint32_t u; } v; v.f = x;
    uint32_t r = v.u + 0x7fffu + ((v.u >> 16) & 1u);
    return (u16)(r >> 16);
}
__device__ __forceinline__ float bf2f(u16 b) {
    union { uint32_t u; float f; } v; v.u = ((uint32_t)b) << 16;
    return v.f;
}
__device__ __forceinline__ bf16x8 cvt8(const float* __restrict__ p) {
    float4 x0 = *(const float4*)p;
    float4 x1 = *(const float4*)(p + 4);
    bf16x8 r;
    r[0]=(short)f2bf(x0.x); r[1]=(short)f2bf(x0.y);
    r[2]=(short)f2bf(x0.z); r[3]=(short)f2bf(x0.w);
    r[4]=(short)f2bf(x1.x); r[5]=(short)f2bf(x1.y);
    r[6]=(short)f2bf(x1.z); r[7]=(short)f2bf(x1.w);
    return r;
}
__device__ __forceinline__ void gload_lds16(const u16* g, u16* l) {
    __builtin_amdgcn_global_load_lds(
        (const __attribute__((address_space(1))) void*)g,
        (__attribute__((address_space(3))) void*)l, 16, 0, 0);
}

// ---------------- K0: convert feat + weights to bf16 -----------------------
__global__ __launch_bounds__(256) void conv_all(
    const float* __restrict__ feat, const float* __restrict__ Wqkv,
    const float* __restrict__ Wproj,
    u16* __restrict__ featb, u16* __restrict__ Wqkvb, u16* __restrict__ Wprojb)
{
    int gid = blockIdx.x*256 + threadIdx.x;          // grid 2048 -> 524288 thr
    for (int c = gid; c < 3200000; c += 2048*256)    // 25.6M feat elems /8
        *(bf16x8*)(featb + (size_t)c*8) = cvt8(feat + (size_t)c*8);
    if (gid < 24576) *(bf16x8*)(Wqkvb + (size_t)gid*8) = cvt8(Wqkv + (size_t)gid*8);
    if (gid < 8192)  *(bf16x8*)(Wprojb + (size_t)gid*8) = cvt8(Wproj + (size_t)gid*8);
}

// ---------------- K1: qkv GEMM, m97 structure -------------------------------
// 128x128 tile, BK=32 double-buffered LDS via global_load_lds(16B),
// 4 waves (2x2 of 64x64), one barrier per K-step. Output layout [n][h][qkv][32].
__global__ __launch_bounds__(256, 4) void qkv_gemm(
    const u16* __restrict__ featb, const u16* __restrict__ Wqkvb,
    const float* __restrict__ bqkv, u16* __restrict__ qkvb)
{
    const int jt = blockIdx.x;    // 0..5
    const int nt = blockIdx.y;    // 0..781
    const int tid = threadIdx.x;
    __shared__ u16 As[2][128*32];
    __shared__ u16 Bs[2][128*32];

    const int n0 = nt*128, j0 = jt*128;
    // LDS slot o = tid*16B -> row = tid>>2, k-chunk = tid&3 (8 u16)
    const int srow = tid >> 2, schk = (tid & 3) * 8;
    const u16* aS = featb + (size_t)(n0 + srow)*256 + schk;   // rows padded to 100096
    const u16* bS = Wqkvb + (size_t)(j0 + srow)*256 + schk;

#define STAGE_QKV(buf, k0) do { \
    gload_lds16(aS + (k0),                   &As[buf][tid*8]); \
    gload_lds16(aS + (size_t)64*256 + (k0),  &As[buf][2048 + tid*8]); \
    gload_lds16(bS + (k0),                   &Bs[buf][tid*8]); \
    gload_lds16(bS + (size_t)64*256 + (k0),  &Bs[buf][2048 + tid*8]); \
  } while (0)

    STAGE_QKV(0, 0);
    __syncthreads();

    const int w = tid>>6, l = tid&63, lr = l&15, lk = l>>4;
    const int r0 = (w>>1)*64, c0 = (w&1)*64;

    f32x4 acc[4][4];
    #pragma unroll
    for (int a=0;a<4;a++)
      #pragma unroll
      for (int b=0;b<4;b++) acc[a][b] = (f32x4)0.0f;

    for (int t=0; t<8; ++t) {
        const int buf = t & 1;
        if (t < 7) STAGE_QKV(buf^1, (t+1)*32);
        bf16x8 af[4], bfr[4];
        #pragma unroll
        for (int f=0;f<4;f++)
            af[f]  = *(const bf16x8*)&As[buf][(r0 + f*16 + lr)*32 + lk*8];
        #pragma unroll
        for (int f=0;f<4;f++)
            bfr[f] = *(const bf16x8*)&Bs[buf][(c0 + f*16 + lr)*32 + lk*8];
        #pragma unroll
        for (int a=0;a<4;a++)
          #pragma unroll
          for (int b=0;b<4;b++)
            acc[a][b] = __builtin_amdgcn_mfma_f32_16x16x32_bf16(af[a], bfr[b], acc[a][b], 0,0,0);
        __syncthreads();
    }
#undef STAGE_QKV

    #pragma unroll
    for (int a=0;a<4;a++) {
      #pragma unroll
      for (int b=0;b<4;b++) {
        int col = j0 + c0 + b*16 + lr;           // 0..767
        float bias = bqkv[col];
        int part = col >> 8, hh = (col >> 5) & 7, d = col & 31;
        size_t cofs = (size_t)hh*96 + part*32 + d;
        #pragma unroll
        for (int r=0;r<4;r++) {
            int row = n0 + r0 + a*16 + lk*4 + r;
            if (row < N_PTS)
                qkvb[(size_t)row*768 + cofs] = f2bf(acc[a][b][r] + bias);
        }
      }
    }
}

// ---------------- K2: gather + RoPE + blocked attention --------------------
// qkvb layout: [n][h][{q,k,v}][32] -> per (token,head) 192B contiguous.
__global__ __launch_bounds__(256) void attn_kernel(
    const u16* __restrict__ qkvb, const int* __restrict__ pinv,
    const float* __restrict__ cosb, const float* __restrict__ sinb,
    u16* __restrict__ attnout)
{
    const int h = blockIdx.x;    // 0..7
    const int p = blockIdx.y;    // 0..1023
    const int tid = threadIdx.x;

    __shared__ u16 qb[128][40];
    __shared__ u16 kb[128][40];
    __shared__ u16 vT[32][136];
    __shared__ u16 Pb[128][136];

    {   // gather + RoPE: 2 threads per token (part0: Q, part1: K + V)
        const int i = tid >> 1, part = tid & 1;
        const int m = p*128 + i;
        const int r = pinv[m];
        const u16* base = qkvb + (size_t)r*768 + h*96 + part*32;
        u16 vals[32];
        *(uint4*)(vals+0)  = *(const uint4*)(base+0);
        *(uint4*)(vals+8)  = *(const uint4*)(base+8);
        *(uint4*)(vals+16) = *(const uint4*)(base+16);
        *(uint4*)(vals+24) = *(const uint4*)(base+24);
        const float* cr = cosb + (size_t)m*32;
        const float* sr = sinb + (size_t)m*32;
        u16 o[32];
        #pragma unroll
        for (int d=0; d<16; d++) {
            float x1 = bf2f(vals[d]), x2 = bf2f(vals[d+16]);
            float c = cr[d], s = sr[d];
            o[d]    = f2bf(x1*c - x2*s);
            o[d+16] = f2bf(x2*c + x1*s);
        }
        u16 (*dst)[40] = part ? kb : qb;
        *(uint4*)&dst[i][0]  = *(uint4*)(o+0);
        *(uint4*)&dst[i][8]  = *(uint4*)(o+8);
        *(uint4*)&dst[i][16] = *(uint4*)(o+16);
        *(uint4*)&dst[i][24] = *(uint4*)(o+24);
        if (part) {
            const u16* vbase = base + 32;   // V slice of this head
            #pragma unroll
            for (int dd=0; dd<32; dd+=8) {
                u16 tv[8];
                *(uint4*)tv = *(const uint4*)(vbase+dd);
                #pragma unroll
                for (int b=0;b<8;b++) vT[dd+b][i] = tv[b];
            }
        }
    }
    __syncthreads();

    const int w = tid>>6, l = tid&63, lr = l&15, lk = l>>4;
    const float scale = 0.17677669529663687f;   // 1/sqrt(32)

    f32x4 sf[2][8];
    #pragma unroll
    for (int mt=0; mt<2; mt++) {
        const int rb = w*32 + mt*16;
        bf16x8 a = *(const bf16x8*)&qb[rb+lr][lk*8];
        #pragma unroll
        for (int nt=0; nt<8; nt++) {
            bf16x8 b = *(const bf16x8*)&kb[nt*16+lr][lk*8];
            sf[mt][nt] = __builtin_amdgcn_mfma_f32_16x16x32_bf16(a, b, (f32x4)0.0f, 0,0,0);
        }
    }
    #pragma unroll
    for (int mt=0; mt<2; mt++) {
      #pragma unroll
      for (int r=0; r<4; r++) {
        float mx = -1e30f;
        #pragma unroll
        for (int nt=0; nt<8; nt++) {
            sf[mt][nt][r] *= scale;
            mx = fmaxf(mx, sf[mt][nt][r]);
        }
        #pragma unroll
        for (int msk=1; msk<16; msk<<=1) mx = fmaxf(mx, __shfl_xor(mx, msk));
        float sum = 0.f;
        #pragma unroll
        for (int nt=0; nt<8; nt++) {
            float e = __expf(sf[mt][nt][r] - mx);
            sf[mt][nt][r] = e;
            sum += e;
        }
        #pragma unroll
        for (int msk=1; msk<16; msk<<=1) sum += __shfl_xor(sum, msk);
        float inv = 1.f / sum;
        int row = w*32 + mt*16 + lk*4 + r;
        #pragma unroll
        for (int nt=0; nt<8; nt++)
            Pb[row][nt*16+lr] = f2bf(sf[mt][nt][r] * inv);
      }
    }
    #pragma unroll
    for (int mt=0; mt<2; mt++) {
        const int rb = w*32 + mt*16;
        #pragma unroll
        for (int nt=0; nt<2; nt++) {
            f32x4 acc = (f32x4)0.0f;
            #pragma unroll
            for (int ks=0; ks<4; ks++) {
                bf16x8 a = *(const bf16x8*)&Pb[rb+lr][ks*32 + lk*8];
                bf16x8 b = *(const bf16x8*)&vT[nt*16+lr][ks*32 + lk*8];
                acc = __builtin_amdgcn_mfma_f32_16x16x32_bf16(a, b, acc, 0,0,0);
            }
            #pragma unroll
            for (int r=0;r<4;r++) {
                int token = p*128 + rb + lk*4 + r;
                attnout[(size_t)token*256 + h*32 + nt*16 + lr] = f2bf(acc[r]);
            }
        }
    }
}

// ---------------- K3: bucket fill (index atomics only) ---------------------
__global__ __launch_bounds__(256) void fill_kernel(const int* __restrict__ pinv,
                                                   int* __restrict__ cursor,
                                                   int* __restrict__ list)
{
    int m = blockIdx.x*256 + threadIdx.x;
    if (m < M_PTS) {
        int seg = pinv[m];
        int slot = atomicAdd(cursor + seg, 1);
        if (slot < 32) list[seg*32 + slot] = m;
    }
}

// ---------------- K4: per-segment mean (gather-reduce, no atomics) ---------
__global__ __launch_bounds__(256) void seg_mean(
    const u16* __restrict__ attnout, const int* __restrict__ cursor,
    const int* __restrict__ list, u16* __restrict__ meanb)
{
    int idx = blockIdx.x*256 + threadIdx.x;   // grid 3125 -> 800000
    int seg = idx >> 3, c8 = idx & 7;
    if (seg >= N_PTS) return;
    int c = cursor[seg];
    int cc = c < 32 ? c : 32;
    float acc[32];
    #pragma unroll
    for (int j=0;j<32;j++) acc[j] = 0.f;
    const int* lp = list + seg*32;
    for (int i=0;i<cc;i++) {
        int m = lp[i];
        const u16* src = attnout + (size_t)m*256 + c8*32;
        #pragma unroll
        for (int ch=0;ch<4;ch++) {
            bf16x8 v = *(const bf16x8*)(src + ch*8);
            #pragma unroll
            for (int j=0;j<8;j++) acc[ch*8+j] += bf2f((u16)v[j]);
        }
    }
    float inv = (c > 0) ? 1.f/(float)c : 0.f;
    u16* dst = meanb + (size_t)seg*256 + c8*32;
    #pragma unroll
    for (int ch=0;ch<4;ch++) {
        bf16x8 o;
        #pragma unroll
        for (int j=0;j<8;j++) o[j] = (short)f2bf(acc[ch*8+j]*inv);
        *(bf16x8*)(dst + ch*8) = o;
    }
}

// ---------------- K5: out = meanb @ Wproj^T + bproj, m97 structure ---------
__global__ __launch_bounds__(256, 4) void mean_proj(
    const u16* __restrict__ meanb, const int* __restrict__ cursor,
    const u16* __restrict__ Wprojb, const float* __restrict__ bproj,
    float* __restrict__ out)
{
    const int jt = blockIdx.x;    // 0..1
    const int nt = blockIdx.y;    // 0..781
    const int tid = threadIdx.x;
    __shared__ u16 As[2][128*32];
    __shared__ u16 Bs[2][128*32];

    const int n0 = nt*128, j0 = jt*128;
    const int srow = tid >> 2, schk = (tid & 3) * 8;
    const u16* aS = meanb  + (size_t)(n0 + srow)*256 + schk;   // rows padded to 100096
    const u16* bS = Wprojb + (size_t)(j0 + srow)*256 + schk;

#define STAGE_MP(buf, k0) do { \
    gload_lds16(aS + (k0),                   &As[buf][tid*8]); \
    gload_lds16(aS + (size_t)64*256 + (k0),  &As[buf][2048 + tid*8]); \
    gload_lds16(bS + (k0),                   &Bs[buf][tid*8]); \
    gload_lds16(bS + (size_t)64*256 + (k0),  &Bs[buf][2048 + tid*8]); \
  } while (0)

    STAGE_MP(0, 0);
    __syncthreads();

    const int w = tid>>6, l = tid&63, lr = l&15, lk = l>>4;
    const int r0 = (w>>1)*64, c0 = (w&1)*64;

    f32x4 acc[4][4];
    #pragma unroll
    for (int a=0;a<4;a++)
      #pragma unroll
      for (int b=0;b<4;b++) acc[a][b] = (f32x4)0.0f;

    for (int t=0; t<8; ++t) {
        const int buf = t & 1;
        if (t < 7) STAGE_MP(buf^1, (t+1)*32);
        bf16x8 af[4], bfr[4];
        #pragma unroll
        for (int f=0;f<4;f++)
            af[f]  = *(const bf16x8*)&As[buf][(r0 + f*16 + lr)*32 + lk*8];
        #pragma unroll
        for (int f=0;f<4;f++)
            bfr[f] = *(const bf16x8*)&Bs[buf][(c0 + f*16 + lr)*32 + lk*8];
        #pragma unroll
        for (int a=0;a<4;a++)
          #pragma unroll
          for (int b=0;b<4;b++)
            acc[a][b] = __builtin_amdgcn_mfma_f32_16x16x32_bf16(af[a], bfr[b], acc[a][b], 0,0,0);
        __syncthreads();
    }
#undef STAGE_MP

    #pragma unroll
    for (int a=0;a<4;a++) {
      #pragma unroll
      for (int b=0;b<4;b++) {
        int col = j0 + c0 + b*16 + lr;
        float bias = bproj[col];
        #pragma unroll
        for (int r=0;r<4;r++) {
            int row = n0 + r0 + a*16 + lk*4 + r;
            if (row < N_PTS) {
                int c = cursor[row];
                out[(size_t)row*256 + col] = (c > 0) ? acc[a][b][r] + bias : 0.f;
            }
        }
      }
    }
}

extern "C" void kernel_launch(void* const* d_in, const int* in_sizes, int n_in,
                              void* d_out, int out_size, void* d_ws, size_t ws_size,
                              hipStream_t stream)
{
    const float* feat  = (const float*)d_in[0];
    const int*   pinv  = (const int*)d_in[2];
    const float* cosb  = (const float*)d_in[4];
    const float* sinb  = (const float*)d_in[5];
    const float* Wqkv  = (const float*)d_in[6];
    const float* bqkv  = (const float*)d_in[7];
    const float* Wproj = (const float*)d_in[8];
    const float* bproj = (const float*)d_in[9];
    float* out = (float*)d_out;

    char* ws = (char*)d_ws;
    u16* qkvb = (u16*)ws;                                  // 153.6 MB (dead after attn)
    u16* meanb = (u16*)ws;                                 // 51.25 MB @ [0, 51.25M) after attn
    int* list  = (int*)(ws + 70000000);                    // 12.8 MB  @ [70M, 82.8M) after attn
    int* cursor= (int*)(ws + 90000000);                    // 0.4 MB   @ [90M, 90.4M) after attn
    size_t off0 = (size_t)N_PTS*768*2;                     // 153.6 MB
    u16* attnout = (u16*)(ws + off0);                      // 67.1 MB
    u16* featb   = (u16*)(ws + off0);                      // 51.25 MB, overlaps attnout
                                                           // (featb dead before attn writes)
    size_t off2 = off0 + (size_t)M_PTS*256*2;
    u16* Wqkvb = (u16*)(ws + off2);                        // 0.39 MB
    size_t off3 = off2 + (size_t)768*256*2;
    u16* Wprojb = (u16*)(ws + off3);                       // 0.13 MB

    conv_all     <<<2048, 256, 0, stream>>>(feat, Wqkv, Wproj, featb, Wqkvb, Wprojb);
    qkv_gemm     <<<dim3(6, 782), 256, 0, stream>>>(featb, Wqkvb, bqkv, qkvb);
    attn_kernel  <<<dim3(8, 1024), 256, 0, stream>>>(qkvb, pinv, cosb, sinb, attnout);
    hipMemsetAsync(cursor, 0, (size_t)N_PTS*sizeof(int), stream);
    fill_kernel  <<<512, 256, 0, stream>>>(pinv, cursor, list);
    seg_mean     <<<3125, 256, 0, stream>>>(attnout, cursor, list, meanb);
    mean_proj    <<<dim3(2, 782), 256, 0, stream>>>(meanb, cursor, Wprojb, bproj, out);
}